// Round 16
// baseline (90.384 us; speedup 1.0000x reference)
//
#include <hip/hip_runtime.h>
#include <cmath>
#include <cfloat>

#define B_N 32
#define A_N 8400
#define G_N 32
#define C_N 80
#define NBLK_A 9             // kAfg: ceil(2100 groups / 256), 4 anchors/thread
#define NPA (NBLK_A * B_N)   // 288 kAfg partials
#define NC1 (G_N * 10)       // 320 entry blocks per batch
#define NPC (NC1 * B_N)      // 10240 kC1 partials
#define FB_STRIDE (NBLK_A * 1024)   // 9216 F_box slots per batch
#define CH10 10              // s0 partial chunks (8 classes each)

// ---------- common device helpers ----------

__device__ __forceinline__ float flog(float x) {
  return __log2f(x) * 0.6931471805599453f;
}

__device__ __forceinline__ float fsqrt(float x) {
  return __builtin_amdgcn_sqrtf(x);
}

__device__ __forceinline__ const float* chan_base(const float* __restrict__ p0,
                                                  const float* __restrict__ p1,
                                                  const float* __restrict__ p2,
                                                  int b, int a, int& cs) {
  if (a < 6400)      { cs = 6400; return p0 + (size_t)b * 85 * 6400 + a; }
  else if (a < 8000) { cs = 1600; return p1 + (size_t)b * 85 * 1600 + (a - 6400); }
  else               { cs = 400;  return p2 + (size_t)b * 85 * 400  + (a - 8000); }
}

__device__ __forceinline__ void anchor_info(int a, float& cx, float& cy, float& st) {
  if (a < 6400)      { int h = a / 80;            int w = a - h * 80; cx = (w + 0.5f) * 8.f;  cy = (h + 0.5f) * 8.f;  st = 8.f;  }
  else if (a < 8000) { int t = a - 6400; int h = t / 40; int w = t - h * 40; cx = (w + 0.5f) * 16.f; cy = (h + 0.5f) * 16.f; st = 16.f; }
  else               { int t = a - 8000; int h = t / 20; int w = t - h * 20; cx = (w + 0.5f) * 32.f; cy = (h + 0.5f) * 32.f; st = 32.f; }
}

__device__ __forceinline__ float pair_iou(float gx, float gy, float gw, float gh,
                                          float px, float py, float pw, float ph) {
  float gx1 = gx - 0.5f * gw, gy1 = gy - 0.5f * gh, gx2 = gx + 0.5f * gw, gy2 = gy + 0.5f * gh;
  float px1 = px - 0.5f * pw, py1 = py - 0.5f * ph, px2 = px + 0.5f * pw, py2 = py + 0.5f * ph;
  float iw = fmaxf(fminf(gx2, px2) - fmaxf(gx1, px1), 0.f);
  float ih = fmaxf(fminf(gy2, py2) - fmaxf(gy1, py1), 0.f);
  float inter = iw * ih;
  return inter / (gw * gh + pw * ph - inter + 1e-16f);
}

// ---------- kernel A1: streaming s0 partials ----------
// block = (level*10 + chunk, b); reads channels [5+chunk*8, +8) of one level for
// one batch: a CONTIGUOUS region of memory (channels adjacent). Channel-major
// sweep; per-thread register accumulators over up to 25 strided anchors.

__global__ __launch_bounds__(256) void kA1(const float* __restrict__ p0, const float* __restrict__ p1,
                                           const float* __restrict__ p2,
                                           float* __restrict__ s0p) {        // [CH10][B_N][A_N]
  int lc = blockIdx.x, b = blockIdx.y, t = threadIdx.x;
  int lvl = lc / CH10, chunk = lc - lvl * CH10;
  int cs    = (lvl == 0) ? 6400 : (lvl == 1) ? 1600 : 400;
  int abase = (lvl == 0) ? 0    : (lvl == 1) ? 6400 : 8000;
  const float* base = (lvl == 0) ? p0 + (size_t)b * 85 * 6400
                    : (lvl == 1) ? p1 + (size_t)b * 85 * 1600
                                 : p2 + (size_t)b * 85 * 400;
  const int c0 = 5 + chunk * 8;

  float objv[25], l2s[25], prod[25];
#pragma unroll
  for (int k = 0; k < 25; ++k) {
    int idx = k * 256 + t;
    objv[k] = (idx < cs) ? base[4 * cs + idx] : 0.f;
    l2s[k] = 0.f;
  }
#pragma unroll
  for (int g = 0; g < 2; ++g) {           // two 4-class log-groups
    // q0*q1 and q2*q3 pairwise, matching original ((q0*q1)*(q2*q3))
    float pa_[25], pb_[25];
#pragma unroll
    for (int cc = 0; cc < 4; ++cc) {
      int ch = c0 + g * 4 + cc;
      const float* row = base + (size_t)ch * cs;
#pragma unroll
      for (int k = 0; k < 25; ++k) {
        int idx = k * 256 + t;
        float v = (idx < cs) ? row[idx] : 0.f;
        float qv = 1.f - fsqrt(v * objv[k]);
        if (cc == 0) pa_[k] = qv;
        else if (cc == 1) pa_[k] *= qv;
        else if (cc == 2) pb_[k] = qv;
        else pb_[k] *= qv;
      }
    }
#pragma unroll
    for (int k = 0; k < 25; ++k)
      l2s[k] += __log2f(fmaxf(pa_[k] * pb_[k], 1e-37f));
  }
  const float LN2 = 0.6931471805599453f;
  float* dst = s0p + ((size_t)chunk * B_N + b) * A_N + abase;
#pragma unroll
  for (int k = 0; k < 25; ++k) {
    int idx = k * 256 + t;
    if (idx < cs) dst[idx] = l2s[k] * LN2;
  }
}

// ---------- kernel Afg: fg mask, box compaction, bg-obj partial (5 channels) ----------

__global__ __launch_bounds__(256) void kAfg(const float* __restrict__ p0, const float* __restrict__ p1,
                                            const float* __restrict__ p2, const float* __restrict__ labels,
                                            unsigned char* __restrict__ fgor,
                                            float4* __restrict__ F_box, int* __restrict__ F_bcnt,
                                            double* __restrict__ partA) {
  int b = blockIdx.y, tid = threadIdx.x;
  int a0 = (blockIdx.x * 256 + tid) * 4;
  __shared__ float4 labf[G_N];
  __shared__ float4 stage[1024];
  __shared__ double robj[4];
  __shared__ int s_cnt;
  bool active = (a0 < A_N);

  if (tid < G_N) {
    const float* L = labels + (size_t)(b * G_N + tid) * 5;
    labf[tid] = make_float4(L[1], L[2], 0.5f * L[3], 0.5f * L[4]);
  }
  if (tid == 0) s_cnt = 0;
  __syncthreads();

  double so = 0.0;
  bool fgj[4] = {false, false, false, false};
  float4 ch0, ch1, ch2, ch3, ob;
  int cs = 0; const float* pp = nullptr;
  if (active) {
    pp = chan_base(p0, p1, p2, b, a0, cs);
    ob  = *(const float4*)(pp + 4 * cs);
    ch0 = *(const float4*)(pp);
    ch1 = *(const float4*)(pp + cs);
    ch2 = *(const float4*)(pp + 2 * cs);
    ch3 = *(const float4*)(pp + 3 * cs);
    so = -((double)fmaxf(flog(1.f - ob.x), -100.f) + (double)fmaxf(flog(1.f - ob.y), -100.f)
         + (double)fmaxf(flog(1.f - ob.z), -100.f) + (double)fmaxf(flog(1.f - ob.w), -100.f));
    uchar4 fgb;
#pragma unroll
    for (int j = 0; j < 4; ++j) {
      float cx, cy, st; anchor_info(a0 + j, cx, cy, st);
      float rr = 2.5f * st;
      bool fg = false;
      for (int g = 0; g < G_N; ++g) {
        float4 L = labf[g];
        float dx = fabsf(cx - L.x), dy = fabsf(cy - L.y);
        fg = fg | ((dx < L.z) & (dy < L.w)) | ((dx < rr) & (dy < rr));
      }
      fgj[j] = fg;
      ((unsigned char*)&fgb)[j] = fg ? 1 : 0;
    }
    *(uchar4*)(fgor + (size_t)b * A_N + a0) = fgb;
#pragma unroll
    for (int j = 0; j < 4; ++j) {
      if (fgj[j]) {
        int pos = atomicAdd(&s_cnt, 1);   // LDS atomic
        float px = (j == 0) ? ch0.x : (j == 1) ? ch0.y : (j == 2) ? ch0.z : ch0.w;
        float py = (j == 0) ? ch1.x : (j == 1) ? ch1.y : (j == 2) ? ch1.z : ch1.w;
        float pw = (j == 0) ? ch2.x : (j == 1) ? ch2.y : (j == 2) ? ch2.z : ch2.w;
        float ph = (j == 0) ? ch3.x : (j == 1) ? ch3.y : (j == 2) ? ch3.z : ch3.w;
        stage[pos] = make_float4(px, py, pw, ph);
      }
    }
  }
  int lane = tid & 63, wv = tid >> 6;
#pragma unroll
  for (int off = 32; off >= 1; off >>= 1) so += __shfl_down(so, off);
  if (lane == 0) robj[wv] = so;
  __syncthreads();
  int cnt = s_cnt;
  if (tid == 0) {
    partA[b * NBLK_A + blockIdx.x] = (robj[0] + robj[1]) + (robj[2] + robj[3]);
    F_bcnt[b * NBLK_A + blockIdx.x] = cnt;
  }
  float4* dst = F_box + (size_t)b * FB_STRIDE + (size_t)blockIdx.x * 1024;
  for (int i = tid; i < cnt; i += 256) dst[i] = stage[i];
}

// ---------- kernel B: per-(b,g) dyn_k + top-k selection; dense -1-padded output ----------

#define LESSCI(c1, i1, c2, i2) (((c1) < (c2)) || ((c1) == (c2) && (i1) < (i2)))

__device__ __forceinline__ float s0_sum(const float* __restrict__ s0p, int b, int a) {
  float s = 0.f;
#pragma unroll
  for (int c = 0; c < CH10; ++c) s += s0p[((size_t)c * B_N + b) * A_N + a];
  return s;
}

__global__ __launch_bounds__(256) void kB(const float* __restrict__ p0, const float* __restrict__ p1,
                                          const float* __restrict__ p2, const float* __restrict__ labels,
                                          const float* __restrict__ s0p, const unsigned char* __restrict__ fgor,
                                          const float4* __restrict__ F_box, const int* __restrict__ F_bcnt,
                                          int* __restrict__ match_idx) {
  int g = blockIdx.x, b = blockIdx.y, tid = threadIdx.x;
  __shared__ float lds_c[10 * 256];
  __shared__ int   lds_i[10 * 256];
  __shared__ float slab[5];
  __shared__ int s_bcnt[NBLK_A];
  __shared__ int s_nV, s_dynk;
  if (tid < 5) slab[tid] = labels[(b * G_N + g) * 5 + tid];
  if (tid < NBLK_A) s_bcnt[tid] = F_bcnt[b * NBLK_A + tid];
  if (tid == 0) s_nV = 0;
  __syncthreads();
  float gx = slab[1], gy = slab[2], gw = slab[3], gh = slab[4];
  int cid = (int)slab[0];

  // ---- phase A: top-10 iou VALUES over segmented fg boxes ----
  float v10[10];
#pragma unroll
  for (int t = 0; t < 10; ++t) v10[t] = 0.f;
  const float4* bx = F_box + (size_t)b * FB_STRIDE;
  for (int j = 0; j < NBLK_A; ++j) {
    int c = s_bcnt[j];
    const float4* cx4 = bx + (size_t)j * 1024;
    for (int i = tid; i < c; i += 256) {
      float4 B = cx4[i];
      float iou = pair_iou(gx, gy, gw, gh, B.x, B.y, B.z, B.w);
      if (iou > v10[9]) {
        float nv = iou;
#pragma unroll
        for (int t = 0; t < 10; ++t)
          if (nv > v10[t]) { float tf = v10[t]; v10[t] = nv; nv = tf; }
      }
    }
  }
#pragma unroll
  for (int t = 0; t < 10; ++t) lds_c[t * 256 + tid] = v10[t];
  __syncthreads();
  for (int s = 128; s >= 1; s >>= 1) {
    if (tid < s) {
      int ca = tid, cb = tid + s;
      float tv[10]; int qa = 0, qb = 0;
#pragma unroll
      for (int t = 0; t < 10; ++t) {
        float va = lds_c[qa * 256 + ca], vb = lds_c[qb * 256 + cb];
        bool ta = va >= vb;
        tv[t] = ta ? va : vb; qa += ta ? 1 : 0; qb += ta ? 0 : 1;
      }
#pragma unroll
      for (int t = 0; t < 10; ++t) lds_c[t * 256 + ca] = tv[t];
    }
    __syncthreads();
  }
  if (tid == 0) {
    float sum = 0.f;
#pragma unroll
    for (int t = 0; t < 10; ++t) sum += lds_c[t * 256];
    int k = (int)sum; if (k < 1) k = 1; if (k > 10) k = 10;
    s_dynk = k;
  }
  __syncthreads();
  int dynk = s_dynk;

  // ---- phase B: geometric valid candidates (<=147), exact cost, s0 = chunk sums ----
  float cc = INFINITY; int ci = 0x7fffffff;
  if (tid < 147) {
    int lvl = tid / 49, r2 = tid % 49;
    int dh = r2 / 7 - 3, dw = r2 % 7 - 3;
    float st = (lvl == 0) ? 8.f : (lvl == 1) ? 16.f : 32.f;
    int Wg = (lvl == 0) ? 80 : (lvl == 1) ? 40 : 20;
    int basea = (lvl == 0) ? 0 : (lvl == 1) ? 6400 : 8000;
    int hc = (int)floorf(gy / st) + dh, wc = (int)floorf(gx / st) + dw;
    if (hc >= 0 && hc < Wg && wc >= 0 && wc < Wg) {
      int a = basea + hc * Wg + wc;
      float cx = (wc + 0.5f) * st, cy = (hc + 0.5f) * st;
      float dx = fabsf(cx - gx), dy = fabsf(cy - gy);
      bool ic = (dx < 2.5f * st) & (dy < 2.5f * st);
      bool ib = (dx < 0.5f * gw) & (dy < 0.5f * gh);
      if (ic && ib) {
        atomicAdd(&s_nV, 1);
        int cs; const float* pp = chan_base(p0, p1, p2, b, a, cs);
        float px = pp[0], py = pp[cs], pw = pp[2 * cs], ph = pp[3 * cs], obj = pp[4 * cs];
        float clsv = pp[(5 + cid) * cs];
        float iou = pair_iou(gx, gy, gw, gh, px, py, pw, ph);
        float p = fsqrt(clsv * obj);
        float l1 = fmaxf(flog(p), -100.f), l0 = fmaxf(flog(1.f - p), -100.f);
        cc = (-l1 + l0 - s0_sum(s0p, b, a)) - 3.f * flog(iou + 1e-8f);
        ci = a;
      }
    }
  }
  lds_c[tid] = cc; lds_i[tid] = ci;
#pragma unroll
  for (int t = 1; t < 10; ++t) { lds_c[t * 256 + tid] = INFINITY; lds_i[t * 256 + tid] = 0x7fffffff; }
  __syncthreads();
  int nV = s_nV;
  for (int s = 128; s >= 1; s >>= 1) {
    if (tid < s) {
      int ca = tid, cb = tid + s;
      float tc[10]; int ti[10]; int pa = 0, pb = 0;
#pragma unroll
      for (int t = 0; t < 10; ++t) {
        float va = lds_c[pa * 256 + ca]; int ia = lds_i[pa * 256 + ca];
        float vb = lds_c[pb * 256 + cb]; int ib = lds_i[pb * 256 + cb];
        bool ta = LESSCI(va, ia, vb, ib) || (va == vb && ia == ib);
        tc[t] = ta ? va : vb; ti[t] = ta ? ia : ib; pa += ta ? 1 : 0; pb += ta ? 0 : 1;
      }
#pragma unroll
      for (int t = 0; t < 10; ++t) { lds_c[t * 256 + ca] = tc[t]; lds_i[t * 256 + ca] = ti[t]; }
    }
    __syncthreads();
  }

  if (dynk <= nV) {   // valid anchors strictly dominate
    if (tid == 0) {
      for (int t = 0; t < 10; ++t)
        match_idx[(b * G_N + g) * 10 + t] = (t < dynk) ? lds_i[t * 256] : -1;
    }
    return;
  }

  // ---- fallback (rare): exact full scan with penalties ----
  float c10[10]; int i10[10];
#pragma unroll
  for (int t = 0; t < 10; ++t) { c10[t] = INFINITY; i10[t] = 0x7fffffff; }
  for (int a = tid; a < A_N; a += 256) {
    float cx, cy, st; anchor_info(a, cx, cy, st);
    int cs; const float* pp = chan_base(p0, p1, p2, b, a, cs);
    float px = pp[0], py = pp[cs], pw = pp[2 * cs], ph = pp[3 * cs], obj = pp[4 * cs];
    float iou = pair_iou(gx, gy, gw, gh, px, py, pw, ph);
    float clsv = pp[(5 + cid) * cs];
    float p = fsqrt(clsv * obj);
    float l1 = fmaxf(flog(p), -100.f), l0 = fmaxf(flog(1.f - p), -100.f);
    float cst = (-l1 + l0 - s0_sum(s0p, b, a)) - 3.f * flog(iou + 1e-8f);
    float dx = fabsf(cx - gx), dy = fabsf(cy - gy);
    bool vb2 = (dx < 0.5f * gw) & (dy < 0.5f * gh);
    bool vc2 = (dx < 2.5f * st) & (dy < 2.5f * st);
    if (!(vb2 && vc2)) cst += 100000.f;
    if (!(fgor[(size_t)b * A_N + a] != 0)) cst += 1e9f;
    if (LESSCI(cst, a, c10[9], i10[9])) {
      float nc = cst; int ni = a;
#pragma unroll
      for (int t = 0; t < 10; ++t) {
        bool lt = LESSCI(nc, ni, c10[t], i10[t]);
        if (lt) { float tf = c10[t]; c10[t] = nc; nc = tf; int ti = i10[t]; i10[t] = ni; ni = ti; }
      }
    }
  }
#pragma unroll
  for (int t = 0; t < 10; ++t) { lds_c[t * 256 + tid] = c10[t]; lds_i[t * 256 + tid] = i10[t]; }
  __syncthreads();
  for (int s = 128; s >= 1; s >>= 1) {
    if (tid < s) {
      int ca = tid, cb = tid + s;
      float tc[10]; int ti[10]; int pa = 0, pb = 0;
#pragma unroll
      for (int t = 0; t < 10; ++t) {
        float va = lds_c[pa * 256 + ca]; int ia = lds_i[pa * 256 + ca];
        float vb = lds_c[pb * 256 + cb]; int ib = lds_i[pb * 256 + cb];
        bool ta = LESSCI(va, ia, vb, ib) || (va == vb && ia == ib);
        tc[t] = ta ? va : vb; ti[t] = ta ? ia : ib; pa += ta ? 1 : 0; pb += ta ? 0 : 1;
      }
#pragma unroll
      for (int t = 0; t < 10; ++t) { lds_c[t * 256 + ca] = tc[t]; lds_i[t * 256 + ca] = ti[t]; }
    }
    __syncthreads();
  }
  if (tid == 0) {
    for (int t = 0; t < 10; ++t)
      match_idx[(b * G_N + g) * 10 + t] = (t < dynk) ? lds_i[t * 256] : -1;
  }
}

// ---------- kernel C1: one wavefront per entry — dedup + argmin + per-entry partial ----------

__global__ __launch_bounds__(64) void kC1(const float* __restrict__ p0, const float* __restrict__ p1,
                                          const float* __restrict__ p2, const float* __restrict__ labels,
                                          const int* __restrict__ match_idx,
                                          float4* __restrict__ partC) {
  int e = blockIdx.x, b = blockIdx.y, lane = threadIdx.x;
  const int* ent = match_idx + (size_t)b * G_N * 10;
  int a = ent[e];

  float4 outv = make_float4(0.f, 0.f, 0.f, 0.f);
  if (a >= 0) {                            // block-uniform
    int cnt = 0, owner = 0x7fffffff;
#pragma unroll
    for (int k = 0; k < 5; ++k) {
      int v = ent[lane + 64 * k];
      unsigned long long m = __ballot(v == a);
      cnt += __popcll(m);
      if (m) owner = min(owner, 64 * k + __ffsll((unsigned long long)m) - 1);
    }

    int cs; const float* pp = chan_base(p0, p1, p2, b, a, cs);
    float px = pp[0], py = pp[cs], pw = pp[2 * cs], ph = pp[3 * cs];
    float obj = pp[4 * cs];

    int gf = e / 10;
    if (cnt > 1) {
      float cx, cy, st; anchor_info(a, cx, cy, st);
      float cost = INFINITY; int idx = 0x7fffffff;
      if (lane < G_N) {
        const float* L = labels + (size_t)(b * G_N + lane) * 5;
        int cid = (int)L[0];
        float g2x = L[1], g2y = L[2], g2w = L[3], g2h = L[4];
        float iou = pair_iou(g2x, g2y, g2w, g2h, px, py, pw, ph);
        float clsv = pp[(5 + cid) * cs];
        float p = fsqrt(clsv * obj);
        float l1 = fmaxf(flog(p), -100.f), l0 = fmaxf(flog(1.f - p), -100.f);
        cost = (-l1 + l0) - 3.f * flog(iou + 1e-8f);   // s0 & fg penalty are column-uniform
        float dx = fabsf(cx - g2x), dy = fabsf(cy - g2y);
        bool vb2 = (dx < 0.5f * g2w) & (dy < 0.5f * g2h);
        bool vc2 = (dx < 2.5f * st) & (dy < 2.5f * st);
        if (!(vb2 && vc2)) cost += 100000.f;
        idx = lane;
      }
#pragma unroll
      for (int off = 32; off >= 1; off >>= 1) {
        float oc = __shfl_xor(cost, off);
        int oi = __shfl_xor(idx, off);
        if (LESSCI(oc, oi, cost, idx)) { cost = oc; idx = oi; }
      }
      gf = idx;
    }

    if (owner == e) {                      // block-uniform: unique accumulator per anchor
      float part = fmaxf(flog(1.f - pp[(5 + lane) * cs]), -100.f);
      if (lane < C_N - 64) part += fmaxf(flog(1.f - pp[(5 + 64 + lane) * cs]), -100.f);
#pragma unroll
      for (int off = 32; off >= 1; off >>= 1) part += __shfl_xor(part, off);
      float s1v = part;

      if (lane == 0) {
        const float* L = labels + (size_t)(b * G_N + gf) * 5;
        float mi = pair_iou(L[1], L[2], L[3], L[4], px, py, pw, ph);
        float l1o = fmaxf(flog(obj), -100.f);
        float l0o = fmaxf(flog(1.f - obj), -100.f);
        int cid = (int)L[0];
        float pc = pp[(5 + cid) * cs];
        float l1c = fmaxf(flog(pc), -100.f);
        float l0c = fmaxf(flog(1.f - pc), -100.f);
        outv = make_float4(l0o - l1o,
                           1.f - mi * mi,
                           -s1v - mi * l1c + mi * l0c,
                           1.f);
      }
    }
  }
  if (lane == 0) partC[(size_t)b * NC1 + e] = outv;    // plain store, every block
}

// ---------- kernel E: deterministic final reduction (1024 threads) ----------

__global__ __launch_bounds__(1024) void kE(const double* __restrict__ partA,
                                           const float4* __restrict__ partC,
                                           float* __restrict__ out) {
  int tid = threadIdx.x;
  double ao = 0.0, ai = 0.0, ac = 0.0, an = 0.0;
  for (int i = tid; i < NPA; i += 1024) ao += partA[i];
#pragma unroll 5
  for (int i = tid; i < NPC; i += 1024) {
    float4 v = partC[i];
    ao += (double)v.x; ai += (double)v.y; ac += (double)v.z; an += (double)v.w;
  }
  __shared__ double ro[1024], ri[1024], rc[1024], rn[1024];
  ro[tid] = ao; ri[tid] = ai; rc[tid] = ac; rn[tid] = an;
  __syncthreads();
  for (int s = 512; s >= 1; s >>= 1) {
    if (tid < s) { ro[tid] += ro[tid + s]; ri[tid] += ri[tid + s]; rc[tid] += rc[tid + s]; rn[tid] += rn[tid + s]; }
    __syncthreads();
  }
  if (tid == 0) {
    float gt = fmaxf((float)rn[0], 1.f);
    float li = (float)((5.0 * ri[0]) / (double)gt);
    float lo = (float)(ro[0] / (double)gt);
    float lc = (float)(rc[0] / (double)gt);
    out[0] = li + lo + lc;
    out[1] = li;
    out[2] = lo;
    out[3] = lc;
    out[4] = gt;
  }
}

// ---------- launch ----------

extern "C" void kernel_launch(void* const* d_in, const int* in_sizes, int n_in,
                              void* d_out, int out_size, void* d_ws, size_t ws_size,
                              hipStream_t stream) {
  const float* p0 = (const float*)d_in[0];
  const float* p1 = (const float*)d_in[1];
  const float* p2 = (const float*)d_in[2];
  const float* labels = (const float*)d_in[3];
  float* out = (float*)d_out;

  char* w = (char*)d_ws;
  auto alloc = [&](size_t bytes) -> void* {
    void* p = (void*)w;
    w += (bytes + 255) & ~(size_t)255;
    return p;
  };
  int* F_bcnt = (int*)alloc((size_t)NPA * sizeof(int));
  double* partA = (double*)alloc((size_t)NPA * sizeof(double));
  float4* partC = (float4*)alloc((size_t)NPC * sizeof(float4));
  float* s0p = (float*)alloc((size_t)CH10 * B_N * A_N * sizeof(float));
  int* match_idx = (int*)alloc((size_t)B_N * G_N * 10 * sizeof(int));
  unsigned char* fgor = (unsigned char*)alloc((size_t)B_N * A_N);
  float4* F_box = (float4*)alloc((size_t)B_N * FB_STRIDE * sizeof(float4));

  dim3 gA1(3 * CH10, B_N);
  kA1<<<gA1, 256, 0, stream>>>(p0, p1, p2, s0p);
  dim3 gAfg(NBLK_A, B_N);
  kAfg<<<gAfg, 256, 0, stream>>>(p0, p1, p2, labels, fgor, F_box, F_bcnt, partA);
  dim3 gB(G_N, B_N);
  kB<<<gB, 256, 0, stream>>>(p0, p1, p2, labels, s0p, fgor, F_box, F_bcnt, match_idx);
  dim3 gC(NC1, B_N);
  kC1<<<gC, 64, 0, stream>>>(p0, p1, p2, labels, match_idx, partC);
  kE<<<1, 1024, 0, stream>>>(partA, partC, out);
}

// Round 17
// 64.467 us; speedup vs baseline: 1.4020x; 1.4020x over previous
//
#include <hip/hip_runtime.h>
#include <cmath>
#include <cfloat>

#define B_N 32
#define A_N 8400
#define G_N 32
#define C_N 80
#define NBLK_A 9             // ceil(2100 groups / 256), 4 anchors/thread
#define NPA (NBLK_A * B_N)   // 288 kA partials (quarter 0 only)
#define NC1 (G_N * 10)       // 320 entry blocks per batch
#define NPC (NC1 * B_N)      // 10240 kC1 partials
#define FB_STRIDE (NBLK_A * 1024)   // 9216 F_box slots per batch
#define QN 4                 // kA class-split quarters, 20 classes each

// ---------- common device helpers ----------

__device__ __forceinline__ float flog(float x) {
  return __log2f(x) * 0.6931471805599453f;
}

// raw v_sqrt_f32 (~2 ulp) — no IEEE fixup chain; tolerance is 75.5 absolute
__device__ __forceinline__ float fsqrt(float x) {
  return __builtin_amdgcn_sqrtf(x);
}

__device__ __forceinline__ const float* chan_base(const float* __restrict__ p0,
                                                  const float* __restrict__ p1,
                                                  const float* __restrict__ p2,
                                                  int b, int a, int& cs) {
  if (a < 6400)      { cs = 6400; return p0 + (size_t)b * 85 * 6400 + a; }
  else if (a < 8000) { cs = 1600; return p1 + (size_t)b * 85 * 1600 + (a - 6400); }
  else               { cs = 400;  return p2 + (size_t)b * 85 * 400  + (a - 8000); }
}

__device__ __forceinline__ void anchor_info(int a, float& cx, float& cy, float& st) {
  if (a < 6400)      { int h = a / 80;            int w = a - h * 80; cx = (w + 0.5f) * 8.f;  cy = (h + 0.5f) * 8.f;  st = 8.f;  }
  else if (a < 8000) { int t = a - 6400; int h = t / 40; int w = t - h * 40; cx = (w + 0.5f) * 16.f; cy = (h + 0.5f) * 16.f; st = 16.f; }
  else               { int t = a - 8000; int h = t / 20; int w = t - h * 20; cx = (w + 0.5f) * 32.f; cy = (h + 0.5f) * 32.f; st = 32.f; }
}

__device__ __forceinline__ float pair_iou(float gx, float gy, float gw, float gh,
                                          float px, float py, float pw, float ph) {
  float gx1 = gx - 0.5f * gw, gy1 = gy - 0.5f * gh, gx2 = gx + 0.5f * gw, gy2 = gy + 0.5f * gh;
  float px1 = px - 0.5f * pw, py1 = py - 0.5f * ph, px2 = px + 0.5f * pw, py2 = py + 0.5f * ph;
  float iw = fmaxf(fminf(gx2, px2) - fmaxf(gx1, px1), 0.f);
  float ih = fmaxf(fminf(gy2, py2) - fmaxf(gy1, py1), 0.f);
  float inter = iw * ih;
  return inter / (gw * gh + pw * ph - inter + 1e-16f);
}

// ---------- kernel A: float4 anchors x compile-time 20-class quarters ----------

__global__ __launch_bounds__(256) void kA(const float* __restrict__ p0, const float* __restrict__ p1,
                                          const float* __restrict__ p2, const float* __restrict__ labels,
                                          float* __restrict__ s0q,           // [QN][B_N][A_N]
                                          unsigned char* __restrict__ fgor,
                                          float4* __restrict__ F_box, int* __restrict__ F_bcnt,
                                          double* __restrict__ partA) {
  int b = blockIdx.y, tid = threadIdx.x, q = blockIdx.z;
  int a0 = (blockIdx.x * 256 + tid) * 4;
  __shared__ float4 labf[G_N];          // (gx, gy, 0.5*gw, 0.5*gh)
  __shared__ float4 stage[1024];
  __shared__ double robj[4];
  __shared__ int s_cnt;
  bool active = (a0 < A_N);             // groups of 4 never straddle level boundaries

  if (q == 0) {
    if (tid < G_N) {
      const float* L = labels + (size_t)(b * G_N + tid) * 5;
      labf[tid] = make_float4(L[1], L[2], 0.5f * L[3], 0.5f * L[4]);
    }
    if (tid == 0) s_cnt = 0;
    __syncthreads();
  }

  int cs = 0; const float* pp = nullptr;
  float4 ob = make_float4(0.f, 0.f, 0.f, 0.f);
  if (active) {
    pp = chan_base(p0, p1, p2, b, a0, cs);
    ob = *(const float4*)(pp + 4 * cs);
    const int qstart = 5 + q * 20;      // compile-time-constant trip count below
    float4 l2s = make_float4(0.f, 0.f, 0.f, 0.f);
#pragma unroll
    for (int c = 0; c < 20; c += 4) {
      float4 v0 = *(const float4*)(pp + (qstart + c)     * cs);
      float4 v1 = *(const float4*)(pp + (qstart + c + 1) * cs);
      float4 v2 = *(const float4*)(pp + (qstart + c + 2) * cs);
      float4 v3 = *(const float4*)(pp + (qstart + c + 3) * cs);
      l2s.x += __log2f(fmaxf(((1.f - fsqrt(v0.x * ob.x)) * (1.f - fsqrt(v1.x * ob.x))) * ((1.f - fsqrt(v2.x * ob.x)) * (1.f - fsqrt(v3.x * ob.x))), 1e-37f));
      l2s.y += __log2f(fmaxf(((1.f - fsqrt(v0.y * ob.y)) * (1.f - fsqrt(v1.y * ob.y))) * ((1.f - fsqrt(v2.y * ob.y)) * (1.f - fsqrt(v3.y * ob.y))), 1e-37f));
      l2s.z += __log2f(fmaxf(((1.f - fsqrt(v0.z * ob.z)) * (1.f - fsqrt(v1.z * ob.z))) * ((1.f - fsqrt(v2.z * ob.z)) * (1.f - fsqrt(v3.z * ob.z))), 1e-37f));
      l2s.w += __log2f(fmaxf(((1.f - fsqrt(v0.w * ob.w)) * (1.f - fsqrt(v1.w * ob.w))) * ((1.f - fsqrt(v2.w * ob.w)) * (1.f - fsqrt(v3.w * ob.w))), 1e-37f));
    }
    const float LN2 = 0.6931471805599453f;
    *(float4*)(s0q + ((size_t)q * B_N + b) * A_N + a0) =
        make_float4(l2s.x * LN2, l2s.y * LN2, l2s.z * LN2, l2s.w * LN2);
  }

  if (q != 0) return;   // uniform per block

  double so = 0.0;
  bool fgj[4] = {false, false, false, false};
  float4 ch0, ch1, ch2, ch3;
  if (active) {
    ch0 = *(const float4*)(pp);
    ch1 = *(const float4*)(pp + cs);
    ch2 = *(const float4*)(pp + 2 * cs);
    ch3 = *(const float4*)(pp + 3 * cs);
    so = -((double)fmaxf(flog(1.f - ob.x), -100.f) + (double)fmaxf(flog(1.f - ob.y), -100.f)
         + (double)fmaxf(flog(1.f - ob.z), -100.f) + (double)fmaxf(flog(1.f - ob.w), -100.f));
    uchar4 fgb;
#pragma unroll
    for (int j = 0; j < 4; ++j) {
      float cx, cy, st; anchor_info(a0 + j, cx, cy, st);
      float rr = 2.5f * st;
      bool fg = false;
      for (int g = 0; g < G_N; ++g) {
        float4 L = labf[g];
        float dx = fabsf(cx - L.x), dy = fabsf(cy - L.y);
        fg = fg | ((dx < L.z) & (dy < L.w)) | ((dx < rr) & (dy < rr));
      }
      fgj[j] = fg;
      ((unsigned char*)&fgb)[j] = fg ? 1 : 0;
    }
    *(uchar4*)(fgor + (size_t)b * A_N + a0) = fgb;
  }
  if (active) {
#pragma unroll
    for (int j = 0; j < 4; ++j) {
      if (fgj[j]) {
        int pos = atomicAdd(&s_cnt, 1);   // LDS atomic
        float px = (j == 0) ? ch0.x : (j == 1) ? ch0.y : (j == 2) ? ch0.z : ch0.w;
        float py = (j == 0) ? ch1.x : (j == 1) ? ch1.y : (j == 2) ? ch1.z : ch1.w;
        float pw = (j == 0) ? ch2.x : (j == 1) ? ch2.y : (j == 2) ? ch2.z : ch2.w;
        float ph = (j == 0) ? ch3.x : (j == 1) ? ch3.y : (j == 2) ? ch3.z : ch3.w;
        stage[pos] = make_float4(px, py, pw, ph);
      }
    }
  }
  // wave-shuffle reduce first (fixed order within wave), then 4 partials in LDS
  int lane = tid & 63, wv = tid >> 6;
#pragma unroll
  for (int off = 32; off >= 1; off >>= 1) so += __shfl_down(so, off);
  if (lane == 0) robj[wv] = so;
  __syncthreads();
  int cnt = s_cnt;
  if (tid == 0) {
    partA[b * NBLK_A + blockIdx.x] = (robj[0] + robj[1]) + (robj[2] + robj[3]);
    F_bcnt[b * NBLK_A + blockIdx.x] = cnt;          // plain store (always written)
  }
  float4* dst = F_box + (size_t)b * FB_STRIDE + (size_t)blockIdx.x * 1024;
  for (int i = tid; i < cnt; i += 256) dst[i] = stage[i];
}

// ---------- kernel B: per-(b,g) dyn_k + top-k selection; dense -1-padded output ----------

#define LESSCI(c1, i1, c2, i2) (((c1) < (c2)) || ((c1) == (c2) && (i1) < (i2)))

__device__ __forceinline__ float s0_sum(const float* __restrict__ s0q, int b, int a) {
  return s0q[(size_t)b * A_N + a]
       + s0q[((size_t)B_N + b) * A_N + a]
       + s0q[((size_t)2 * B_N + b) * A_N + a]
       + s0q[((size_t)3 * B_N + b) * A_N + a];
}

__global__ __launch_bounds__(256) void kB(const float* __restrict__ p0, const float* __restrict__ p1,
                                          const float* __restrict__ p2, const float* __restrict__ labels,
                                          const float* __restrict__ s0q, const unsigned char* __restrict__ fgor,
                                          const float4* __restrict__ F_box, const int* __restrict__ F_bcnt,
                                          int* __restrict__ match_idx) {
  int g = blockIdx.x, b = blockIdx.y, tid = threadIdx.x;
  __shared__ float lds_c[10 * 256];
  __shared__ int   lds_i[10 * 256];
  __shared__ float slab[5];
  __shared__ int s_bcnt[NBLK_A];
  __shared__ int s_nV, s_dynk;
  if (tid < 5) slab[tid] = labels[(b * G_N + g) * 5 + tid];
  if (tid < NBLK_A) s_bcnt[tid] = F_bcnt[b * NBLK_A + tid];
  if (tid == 0) s_nV = 0;
  __syncthreads();
  float gx = slab[1], gy = slab[2], gw = slab[3], gh = slab[4];
  int cid = (int)slab[0];

  // ---- phase A: top-10 iou VALUES over segmented fg boxes ----
  float v10[10];
#pragma unroll
  for (int t = 0; t < 10; ++t) v10[t] = 0.f;
  const float4* bx = F_box + (size_t)b * FB_STRIDE;
  for (int j = 0; j < NBLK_A; ++j) {
    int c = s_bcnt[j];
    const float4* cx4 = bx + (size_t)j * 1024;
    for (int i = tid; i < c; i += 256) {
      float4 B = cx4[i];
      float iou = pair_iou(gx, gy, gw, gh, B.x, B.y, B.z, B.w);
      if (iou > v10[9]) {
        float nv = iou;
#pragma unroll
        for (int t = 0; t < 10; ++t)
          if (nv > v10[t]) { float tf = v10[t]; v10[t] = nv; nv = tf; }
      }
    }
  }
#pragma unroll
  for (int t = 0; t < 10; ++t) lds_c[t * 256 + tid] = v10[t];
  __syncthreads();
  for (int s = 128; s >= 1; s >>= 1) {
    if (tid < s) {
      int ca = tid, cb = tid + s;
      float tv[10]; int qa = 0, qb = 0;
#pragma unroll
      for (int t = 0; t < 10; ++t) {
        float va = lds_c[qa * 256 + ca], vb = lds_c[qb * 256 + cb];
        bool ta = va >= vb;
        tv[t] = ta ? va : vb; qa += ta ? 1 : 0; qb += ta ? 0 : 1;
      }
#pragma unroll
      for (int t = 0; t < 10; ++t) lds_c[t * 256 + ca] = tv[t];
    }
    __syncthreads();
  }
  if (tid == 0) {
    float sum = 0.f;
#pragma unroll
    for (int t = 0; t < 10; ++t) sum += lds_c[t * 256];
    int k = (int)sum; if (k < 1) k = 1; if (k > 10) k = 10;
    s_dynk = k;
  }
  __syncthreads();
  int dynk = s_dynk;

  // ---- phase B: geometric valid candidates (<=147), exact cost, s0 = quarter sums ----
  float cc = INFINITY; int ci = 0x7fffffff;
  if (tid < 147) {
    int lvl = tid / 49, r2 = tid % 49;
    int dh = r2 / 7 - 3, dw = r2 % 7 - 3;
    float st = (lvl == 0) ? 8.f : (lvl == 1) ? 16.f : 32.f;
    int Wg = (lvl == 0) ? 80 : (lvl == 1) ? 40 : 20;
    int basea = (lvl == 0) ? 0 : (lvl == 1) ? 6400 : 8000;
    int hc = (int)floorf(gy / st) + dh, wc = (int)floorf(gx / st) + dw;
    if (hc >= 0 && hc < Wg && wc >= 0 && wc < Wg) {
      int a = basea + hc * Wg + wc;
      float cx = (wc + 0.5f) * st, cy = (hc + 0.5f) * st;
      float dx = fabsf(cx - gx), dy = fabsf(cy - gy);
      bool ic = (dx < 2.5f * st) & (dy < 2.5f * st);
      bool ib = (dx < 0.5f * gw) & (dy < 0.5f * gh);
      if (ic && ib) {
        atomicAdd(&s_nV, 1);
        int cs; const float* pp = chan_base(p0, p1, p2, b, a, cs);
        float px = pp[0], py = pp[cs], pw = pp[2 * cs], ph = pp[3 * cs], obj = pp[4 * cs];
        float clsv = pp[(5 + cid) * cs];
        float iou = pair_iou(gx, gy, gw, gh, px, py, pw, ph);
        float p = fsqrt(clsv * obj);
        float l1 = fmaxf(flog(p), -100.f), l0 = fmaxf(flog(1.f - p), -100.f);
        cc = (-l1 + l0 - s0_sum(s0q, b, a)) - 3.f * flog(iou + 1e-8f);
        ci = a;
      }
    }
  }
  lds_c[tid] = cc; lds_i[tid] = ci;
#pragma unroll
  for (int t = 1; t < 10; ++t) { lds_c[t * 256 + tid] = INFINITY; lds_i[t * 256 + tid] = 0x7fffffff; }
  __syncthreads();
  int nV = s_nV;
  for (int s = 128; s >= 1; s >>= 1) {
    if (tid < s) {
      int ca = tid, cb = tid + s;
      float tc[10]; int ti[10]; int pa = 0, pb = 0;
#pragma unroll
      for (int t = 0; t < 10; ++t) {
        float va = lds_c[pa * 256 + ca]; int ia = lds_i[pa * 256 + ca];
        float vb = lds_c[pb * 256 + cb]; int ib = lds_i[pb * 256 + cb];
        bool ta = LESSCI(va, ia, vb, ib) || (va == vb && ia == ib);
        tc[t] = ta ? va : vb; ti[t] = ta ? ia : ib; pa += ta ? 1 : 0; pb += ta ? 0 : 1;
      }
#pragma unroll
      for (int t = 0; t < 10; ++t) { lds_c[t * 256 + ca] = tc[t]; lds_i[t * 256 + ca] = ti[t]; }
    }
    __syncthreads();
  }

  if (dynk <= nV) {   // valid anchors strictly dominate
    if (tid == 0) {
      for (int t = 0; t < 10; ++t)
        match_idx[(b * G_N + g) * 10 + t] = (t < dynk) ? lds_i[t * 256] : -1;
    }
    return;
  }

  // ---- fallback (rare): exact full scan with penalties, s0 = quarter sums ----
  float c10[10]; int i10[10];
#pragma unroll
  for (int t = 0; t < 10; ++t) { c10[t] = INFINITY; i10[t] = 0x7fffffff; }
  for (int a = tid; a < A_N; a += 256) {
    float cx, cy, st; anchor_info(a, cx, cy, st);
    int cs; const float* pp = chan_base(p0, p1, p2, b, a, cs);
    float px = pp[0], py = pp[cs], pw = pp[2 * cs], ph = pp[3 * cs], obj = pp[4 * cs];
    float iou = pair_iou(gx, gy, gw, gh, px, py, pw, ph);
    float clsv = pp[(5 + cid) * cs];
    float p = fsqrt(clsv * obj);
    float l1 = fmaxf(flog(p), -100.f), l0 = fmaxf(flog(1.f - p), -100.f);
    float cst = (-l1 + l0 - s0_sum(s0q, b, a)) - 3.f * flog(iou + 1e-8f);
    float dx = fabsf(cx - gx), dy = fabsf(cy - gy);
    bool vb2 = (dx < 0.5f * gw) & (dy < 0.5f * gh);
    bool vc2 = (dx < 2.5f * st) & (dy < 2.5f * st);
    if (!(vb2 && vc2)) cst += 100000.f;
    if (!(fgor[(size_t)b * A_N + a] != 0)) cst += 1e9f;
    if (LESSCI(cst, a, c10[9], i10[9])) {
      float nc = cst; int ni = a;
#pragma unroll
      for (int t = 0; t < 10; ++t) {
        bool lt = LESSCI(nc, ni, c10[t], i10[t]);
        if (lt) { float tf = c10[t]; c10[t] = nc; nc = tf; int ti = i10[t]; i10[t] = ni; ni = ti; }
      }
    }
  }
#pragma unroll
  for (int t = 0; t < 10; ++t) { lds_c[t * 256 + tid] = c10[t]; lds_i[t * 256 + tid] = i10[t]; }
  __syncthreads();
  for (int s = 128; s >= 1; s >>= 1) {
    if (tid < s) {
      int ca = tid, cb = tid + s;
      float tc[10]; int ti[10]; int pa = 0, pb = 0;
#pragma unroll
      for (int t = 0; t < 10; ++t) {
        float va = lds_c[pa * 256 + ca]; int ia = lds_i[pa * 256 + ca];
        float vb = lds_c[pb * 256 + cb]; int ib = lds_i[pb * 256 + cb];
        bool ta = LESSCI(va, ia, vb, ib) || (va == vb && ia == ib);
        tc[t] = ta ? va : vb; ti[t] = ta ? ia : ib; pa += ta ? 1 : 0; pb += ta ? 0 : 1;
      }
#pragma unroll
      for (int t = 0; t < 10; ++t) { lds_c[t * 256 + ca] = tc[t]; lds_i[t * 256 + ca] = ti[t]; }
    }
    __syncthreads();
  }
  if (tid == 0) {
    for (int t = 0; t < 10; ++t)
      match_idx[(b * G_N + g) * 10 + t] = (t < dynk) ? lds_i[t * 256] : -1;
  }
}

// ---------- kernel C1: one wavefront per entry — dedup + argmin + per-entry partial ----------

__global__ __launch_bounds__(64) void kC1(const float* __restrict__ p0, const float* __restrict__ p1,
                                          const float* __restrict__ p2, const float* __restrict__ labels,
                                          const int* __restrict__ match_idx,
                                          float4* __restrict__ partC) {
  int e = blockIdx.x, b = blockIdx.y, lane = threadIdx.x;
  const int* ent = match_idx + (size_t)b * G_N * 10;
  int a = ent[e];

  float4 outv = make_float4(0.f, 0.f, 0.f, 0.f);
  if (a >= 0) {                            // block-uniform
    int cnt = 0, owner = 0x7fffffff;
#pragma unroll
    for (int k = 0; k < 5; ++k) {
      int v = ent[lane + 64 * k];
      unsigned long long m = __ballot(v == a);
      cnt += __popcll(m);
      if (m) owner = min(owner, 64 * k + __ffsll((unsigned long long)m) - 1);
    }

    int cs; const float* pp = chan_base(p0, p1, p2, b, a, cs);
    float px = pp[0], py = pp[cs], pw = pp[2 * cs], ph = pp[3 * cs];
    float obj = pp[4 * cs];

    int gf = e / 10;
    if (cnt > 1) {
      float cx, cy, st; anchor_info(a, cx, cy, st);
      float cost = INFINITY; int idx = 0x7fffffff;
      if (lane < G_N) {
        const float* L = labels + (size_t)(b * G_N + lane) * 5;
        int cid = (int)L[0];
        float g2x = L[1], g2y = L[2], g2w = L[3], g2h = L[4];
        float iou = pair_iou(g2x, g2y, g2w, g2h, px, py, pw, ph);
        float clsv = pp[(5 + cid) * cs];
        float p = fsqrt(clsv * obj);
        float l1 = fmaxf(flog(p), -100.f), l0 = fmaxf(flog(1.f - p), -100.f);
        cost = (-l1 + l0) - 3.f * flog(iou + 1e-8f);   // s0 & fg penalty are column-uniform
        float dx = fabsf(cx - g2x), dy = fabsf(cy - g2y);
        bool vb2 = (dx < 0.5f * g2w) & (dy < 0.5f * g2h);
        bool vc2 = (dx < 2.5f * st) & (dy < 2.5f * st);
        if (!(vb2 && vc2)) cost += 100000.f;
        idx = lane;
      }
#pragma unroll
      for (int off = 32; off >= 1; off >>= 1) {
        float oc = __shfl_xor(cost, off);
        int oi = __shfl_xor(idx, off);
        if (LESSCI(oc, oi, cost, idx)) { cost = oc; idx = oi; }
      }
      gf = idx;
    }

    if (owner == e) {                      // block-uniform: unique accumulator per anchor
      // wave-parallel s1 = sum_c clip(log(1-cls_c), -100)
      float part = fmaxf(flog(1.f - pp[(5 + lane) * cs]), -100.f);
      if (lane < C_N - 64) part += fmaxf(flog(1.f - pp[(5 + 64 + lane) * cs]), -100.f);
#pragma unroll
      for (int off = 32; off >= 1; off >>= 1) part += __shfl_xor(part, off);
      float s1v = part;

      if (lane == 0) {
        const float* L = labels + (size_t)(b * G_N + gf) * 5;
        float mi = pair_iou(L[1], L[2], L[3], L[4], px, py, pw, ph);
        float l1o = fmaxf(flog(obj), -100.f);
        float l0o = fmaxf(flog(1.f - obj), -100.f);
        int cid = (int)L[0];
        float pc = pp[(5 + cid) * cs];
        float l1c = fmaxf(flog(pc), -100.f);
        float l0c = fmaxf(flog(1.f - pc), -100.f);
        outv = make_float4(l0o - l1o,
                           1.f - mi * mi,
                           -s1v - mi * l1c + mi * l0c,
                           1.f);
      }
    }
  }
  if (lane == 0) partC[(size_t)b * NC1 + e] = outv;    // plain store, every block
}

// ---------- kernel E: deterministic final reduction (1024 threads) ----------

__global__ __launch_bounds__(1024) void kE(const double* __restrict__ partA,
                                           const float4* __restrict__ partC,
                                           float* __restrict__ out) {
  int tid = threadIdx.x;
  double ao = 0.0, ai = 0.0, ac = 0.0, an = 0.0;
  for (int i = tid; i < NPA; i += 1024) ao += partA[i];
#pragma unroll 5
  for (int i = tid; i < NPC; i += 1024) {
    float4 v = partC[i];
    ao += (double)v.x; ai += (double)v.y; ac += (double)v.z; an += (double)v.w;
  }
  __shared__ double ro[1024], ri[1024], rc[1024], rn[1024];
  ro[tid] = ao; ri[tid] = ai; rc[tid] = ac; rn[tid] = an;
  __syncthreads();
  for (int s = 512; s >= 1; s >>= 1) {
    if (tid < s) { ro[tid] += ro[tid + s]; ri[tid] += ri[tid + s]; rc[tid] += rc[tid + s]; rn[tid] += rn[tid + s]; }
    __syncthreads();
  }
  if (tid == 0) {
    float gt = fmaxf((float)rn[0], 1.f);
    float li = (float)((5.0 * ri[0]) / (double)gt);
    float lo = (float)(ro[0] / (double)gt);
    float lc = (float)(rc[0] / (double)gt);
    out[0] = li + lo + lc;
    out[1] = li;
    out[2] = lo;
    out[3] = lc;
    out[4] = gt;
  }
}

// ---------- launch ----------

extern "C" void kernel_launch(void* const* d_in, const int* in_sizes, int n_in,
                              void* d_out, int out_size, void* d_ws, size_t ws_size,
                              hipStream_t stream) {
  const float* p0 = (const float*)d_in[0];
  const float* p1 = (const float*)d_in[1];
  const float* p2 = (const float*)d_in[2];
  const float* labels = (const float*)d_in[3];
  float* out = (float*)d_out;

  char* w = (char*)d_ws;
  auto alloc = [&](size_t bytes) -> void* {
    void* p = (void*)w;
    w += (bytes + 255) & ~(size_t)255;
    return p;
  };
  int* F_bcnt = (int*)alloc((size_t)NPA * sizeof(int));
  double* partA = (double*)alloc((size_t)NPA * sizeof(double));
  float4* partC = (float4*)alloc((size_t)NPC * sizeof(float4));
  float* s0q = (float*)alloc((size_t)QN * B_N * A_N * sizeof(float));
  int* match_idx = (int*)alloc((size_t)B_N * G_N * 10 * sizeof(int));
  unsigned char* fgor = (unsigned char*)alloc((size_t)B_N * A_N);
  float4* F_box = (float4*)alloc((size_t)B_N * FB_STRIDE * sizeof(float4));

  dim3 gA(NBLK_A, B_N, QN);
  kA<<<gA, 256, 0, stream>>>(p0, p1, p2, labels, s0q, fgor, F_box, F_bcnt, partA);
  dim3 gB(G_N, B_N);
  kB<<<gB, 256, 0, stream>>>(p0, p1, p2, labels, s0q, fgor, F_box, F_bcnt, match_idx);
  dim3 gC(NC1, B_N);
  kC1<<<gC, 64, 0, stream>>>(p0, p1, p2, labels, match_idx, partC);
  kE<<<1, 1024, 0, stream>>>(partA, partC, out);
}